// Round 8
// baseline (10134.212 us; speedup 1.0000x reference)
//
#include <hip/hip_runtime.h>
#include <hip/hip_bf16.h>
#include <cstdint>

#define B_ 32
#define L_ 196
#define D_ 512
#define H_ 512
#define E_ 256
#define T_ 128
#define V_ 512
#define GRID_ 256
#define NBARS 8576
// bars (ints): [0..4095] init slots (blk*16); [4096..4351] init release (16 lines);
// [4352..8447] group slots ((g*32+r)*16); [8448..8575] group release (g*16).

using u16 = unsigned short;

__device__ __forceinline__ float bf2f(u16 u) { return __uint_as_float(((unsigned)u) << 16); }
__device__ __forceinline__ u16 f2bf(float f) {
    unsigned u = __float_as_uint(f);
    return (u16)((u + 0x7FFFu + ((u >> 16) & 1u)) >> 16);
}
__device__ __forceinline__ float2 bfp(unsigned u) {
    return make_float2(__uint_as_float(u << 16), __uint_as_float(u & 0xffff0000u));
}
__device__ __forceinline__ float sigm(float x) { return 1.f / (1.f + __expf(-x)); }
__device__ __forceinline__ float tanh_fast(float x) { return 1.f - 2.f / (__expf(2.f * x) + 1.f); }

// --- coherent (cache-bypass) payload access: relaxed agent-scope atomics.
__device__ __forceinline__ float ldcf(const float* p) {
    return __hip_atomic_load((float*)p, __ATOMIC_RELAXED, __HIP_MEMORY_SCOPE_AGENT);
}
__device__ __forceinline__ int ldci(const int* p) {
    return __hip_atomic_load((int*)p, __ATOMIC_RELAXED, __HIP_MEMORY_SCOPE_AGENT);
}
__device__ __forceinline__ unsigned ldc32(const void* p) {
    return __hip_atomic_load((unsigned*)p, __ATOMIC_RELAXED, __HIP_MEMORY_SCOPE_AGENT);
}
__device__ __forceinline__ void stcf(float* p, float v) {
    __hip_atomic_store(p, v, __ATOMIC_RELAXED, __HIP_MEMORY_SCOPE_AGENT);
}
__device__ __forceinline__ void stci(int* p, int v) {
    __hip_atomic_store(p, v, __ATOMIC_RELAXED, __HIP_MEMORY_SCOPE_AGENT);
}
__device__ __forceinline__ void stcu(unsigned* p, unsigned v) {
    __hip_atomic_store(p, v, __ATOMIC_RELAXED, __HIP_MEMORY_SCOPE_AGENT);
}
__device__ __forceinline__ void stcu64(unsigned long long* p, unsigned long long v) {
    __hip_atomic_store(p, v, __ATOMIC_RELAXED, __HIP_MEMORY_SCOPE_AGENT);
}

// ---------------- dtype detect + barrier reset ----------------
__global__ void detect_kernel(const u16* __restrict__ w, int* __restrict__ flg,
                              int* __restrict__ bars) {
    for (int i = threadIdx.x; i < NBARS; i += 64) bars[i] = 0;
    if (threadIdx.x == 0) {
        int cnt = 0;
        for (int i = 0; i < 64; ++i) {
            int e = (w[i] >> 7) & 0xFF;
            cnt += (e >= 100 && e <= 130);
        }
        flg[0] = (cnt >= 56) ? 1 : 0;
    }
}

// ---------------- convert all float tensors to internal bf16 ----------------
struct ConvPtrs { const void* p[19]; };

__global__ __launch_bounds__(256) void conv_kernel(ConvPtrs cp, const int* __restrict__ flg,
                                                   u16* __restrict__ dst) {
    constexpr int NT = 19;
    constexpr unsigned off[NT + 1] = {
        0u, 3211264u, 3227648u, 3244032u, 3506176u, 3506432u, 3539200u, 3539328u,
        3539456u, 5112320u, 6160896u, 6162944u, 6164992u, 6296064u, 6754304u,
        6754664u, 6882832u, 6883192u, 7066488u, 7067000u};
    constexpr unsigned realN[NT] = {
        3211264u, 16384u, 16384u, 262144u, 256u, 32768u, 128u, 128u,
        1572864u, 1048576u, 2048u, 2048u, 131072u, 458240u, 358u,
        128164u, 358u, 183296u, 512u};
    unsigned pos = (blockIdx.x * 256u + threadIdx.x) * 4u;
    if (pos >= off[NT]) return;
    int t = 0;
#pragma unroll
    for (int i = 1; i < NT; ++i) t += (pos >= off[i]);
    unsigned local = pos - off[t];
    int bf = flg[0];
    const void* src = cp.p[t];
    u16* d = dst + off[t];
#pragma unroll
    for (int j = 0; j < 4; ++j) {
        unsigned l = local + j;
        u16 v = 0;
        if (l < realN[t]) v = bf ? ((const u16*)src)[l] : f2bf(((const float*)src)[l]);
        d[l] = v;
    }
}

// ---------------- weight prep: wS (k-major concat), w1hT, w2T ----------------
__global__ __launch_bounds__(256) void prep_kernel(const u16* __restrict__ w_ih,
                                                   const u16* __restrict__ w_hh,
                                                   const u16* __restrict__ att_w1,
                                                   const u16* __restrict__ att_w2,
                                                   u16* __restrict__ wS,
                                                   u16* __restrict__ w1hT,
                                                   u16* __restrict__ w2T) {
    int c = blockIdx.x, t = threadIdx.x;
    if (c < 1280) {
        const u16* srcw = (c < 768) ? (w_ih + (size_t)c * 2048) : (w_hh + (size_t)(c - 768) * 2048);
        *(uint4*)(wS + (size_t)c * 2048 + 8 * t) = *(const uint4*)(srcw + 8 * t);
    } else if (c < 1536) {
        int c2 = c - 1280;
#pragma unroll
        for (int i = 0; i < 2; ++i) {
            int k = i * 256 + t;
            w1hT[(size_t)c2 * 512 + k] = att_w1[(size_t)(512 + k) * 256 + c2];
        }
    } else {
        int c3 = c - 1536;
        w2T[c3 * 256 + t] = att_w2[(size_t)t * 128 + c3];
    }
}

// ---------------- embedding (shifted y) -> hze e-part ----------------
__global__ __launch_bounds__(256) void embed_kernel(const int* __restrict__ y,
                                                    const u16* __restrict__ emb,
                                                    u16* __restrict__ hze) {
    int t = threadIdx.x;
    int row0 = blockIdx.x * 4;
    for (int i = 0; i < 4; ++i) {
        int row = row0 + i;
        int b = row >> 7, tt = row & 127;
        int yin = tt ? y[b * T_ + tt - 1] : 0;
        hze[(size_t)row * 1280 + 1024 + t] = emb[yin * E_ + t];
    }
}

// ---------------- generic tiled GEMM: C = act(A @ Bw + bias) ----------------
template <bool TANH, int OMODE>
__global__ __launch_bounds__(256) void gemm_kernel(const u16* __restrict__ A, int lda,
                                                   const u16* __restrict__ Bw, int ldb,
                                                   const u16* __restrict__ bias,
                                                   void* __restrict__ Cv, int ldc,
                                                   int M, int N, int K,
                                                   const int* __restrict__ flg) {
    __shared__ float As[16][132];
    __shared__ float Bs[16][68];
    int t = threadIdx.x;
    int n0 = blockIdx.x * 64;
    int m0 = blockIdx.y * 128;
    int tx = t & 15, ty = t >> 4;
    float acc[8][4];
#pragma unroll
    for (int i = 0; i < 8; ++i)
#pragma unroll
        for (int j = 0; j < 4; ++j) acc[i][j] = 0.f;

    int ar = t >> 1, akb = (t & 1) * 8;
    int bn = t & 63, bkg = t >> 6;

    for (int k0 = 0; k0 < K; k0 += 16) {
        const u16* Ap = A + (size_t)(m0 + ar) * lda + k0 + akb;
        if (k0 + 16 <= K) {
#pragma unroll
            for (int i = 0; i < 8; ++i) As[akb + i][ar] = bf2f(Ap[i]);
        } else {
#pragma unroll
            for (int i = 0; i < 8; ++i) As[akb + i][ar] = (k0 + akb + i < K) ? bf2f(Ap[i]) : 0.f;
        }
#pragma unroll
        for (int i = 0; i < 4; ++i) {
            int kk = bkg * 4 + i;
            int kg = k0 + kk, ng = n0 + bn;
            Bs[kk][bn] = (kg < K && ng < N) ? bf2f(Bw[(size_t)kg * ldb + ng]) : 0.f;
        }
        __syncthreads();
#pragma unroll
        for (int kk = 0; kk < 16; ++kk) {
            float4 aA = *(const float4*)&As[kk][ty * 8];
            float4 aB = *(const float4*)&As[kk][ty * 8 + 4];
            float4 bv = *(const float4*)&Bs[kk][tx * 4];
            float av[8] = {aA.x, aA.y, aA.z, aA.w, aB.x, aB.y, aB.z, aB.w};
            float bb[4] = {bv.x, bv.y, bv.z, bv.w};
#pragma unroll
            for (int i = 0; i < 8; ++i)
#pragma unroll
                for (int j = 0; j < 4; ++j) acc[i][j] += av[i] * bb[j];
        }
        __syncthreads();
    }
    int obf = (OMODE == 2) ? flg[0] : 1;
    float bb[4];
#pragma unroll
    for (int j = 0; j < 4; ++j) {
        int n = n0 + tx * 4 + j;
        bb[j] = (n < N) ? bf2f(bias[n]) : 0.f;
    }
#pragma unroll
    for (int i = 0; i < 8; ++i) {
        int m = m0 + ty * 8 + i;
#pragma unroll
        for (int j = 0; j < 4; ++j) {
            int n = n0 + tx * 4 + j;
            if (n < N) {
                float v = acc[i][j] + bb[j];
                if (TANH) v = tanhf(v);
                if (OMODE == 1 || obf)
                    ((u16*)Cv)[(size_t)m * ldc + n] = f2bf(v);
                else
                    ((float*)Cv)[(size_t)m * ldc + n] = v;
            }
        }
    }
}

// ---------------- persistent decoder: XCD-local groups, NO grid sync in t-loop ----------------
struct DecArgs {
    const u16 *h0, *c0, *pre1, *w2T, *att_b2, *att_w3, *w1hT, *wS, *bih, *bhh, *a;
    u16 *hze, *h0b, *P;
    float *s_buf, *c_buf;
    int* bars;
};

struct SA { float x1s[28][264]; float part[28][36]; };
struct SB { float red[256]; float alpha[200]; float zred[64][5]; };
union SU { SA a; SB b; float hs[512]; };

// one-time init barrier across all 256 blocks (round-7 style)
__device__ __forceinline__ void gridbar(int* bars, int blk, int t, int epoch) {
    __syncthreads();
    if (t == 0) stci(&bars[blk << 4], epoch);
    if (blk == 0) {
        for (;;) {
            int v = ldci(&bars[t << 4]);
            if (__syncthreads_count(v < epoch) == 0) break;
            __builtin_amdgcn_s_sleep(4);
        }
        if (t < 16) stci(&bars[4096 + (t << 4)], epoch);
        __syncthreads();
    } else {
        if (t == 0) {
            while (ldci(&bars[4096 + ((blk & 15) << 4)]) < epoch)
                __builtin_amdgcn_s_sleep(8);
        }
        __syncthreads();
    }
}

// group barrier: 32 blocks, store-slot + rank-0 checker, all relaxed.
__device__ __forceinline__ void gbar(int* bars, int g, int r, int t, int ep) {
    __syncthreads();
    if (t == 0) stci(&bars[4352 + (((g << 5) + r) << 4)], ep);
    if (r == 0) {
        for (;;) {
            int v = (t < 32) ? ldci(&bars[4352 + (((g << 5) + t) << 4)]) : ep;
            if (__syncthreads_count(v < ep) == 0) break;
            __builtin_amdgcn_s_sleep(2);
        }
        if (t == 0) stci(&bars[8448 + (g << 4)], ep);
        __syncthreads();
    } else {
        if (t == 0) {
            while (ldci(&bars[8448 + (g << 4)]) < ep) __builtin_amdgcn_s_sleep(2);
        }
        __syncthreads();
    }
}

__global__ __launch_bounds__(256) void decoder_kernel(DecArgs gd) {
    int blk = blockIdx.x, t = threadIdx.x;
    int g = blk & 7, r = blk >> 3;          // group (XCD heuristic), rank
    int bA = g * 4 + (r >> 3), ach = r & 7; // stage A/B batch + L-chunk
    int kr0 = r * 40;                       // gates k-shard
    __shared__ SU su;
    __shared__ float xs[40][5];
    __shared__ float biasv[64];
    __shared__ float gsum[4][4][16];
    __shared__ float hsh2[4][16];
    __shared__ float w3s[128], b2s[128];

    if (t < 128) {
        w3s[t] = bf2f(gd.att_w3[t]);
        b2s[t] = bf2f(gd.att_b2[t]);
    }
    if (t < 64) {  // biases for this block's gate cols: col = q*512 + 16r + i
        int q = t >> 4, i = t & 15;
        int col = q * 512 + 16 * r + i;
        biasv[t] = bf2f(gd.bih[col]) + bf2f(gd.bhh[col]);
    }
    if (blk < 32) {
        for (int i = t; i < 512; i += 256)
            stcf(&gd.c_buf[blk * 512 + i], bf2f(gd.c0[blk * 512 + i]));
        unsigned pk = (unsigned)gd.h0[blk * 512 + 2 * t] |
                      ((unsigned)gd.h0[blk * 512 + 2 * t + 1] << 16);
        stcu((unsigned*)(gd.h0b + blk * 512 + 2 * t), pk);
    }
    gridbar(gd.bars, blk, t, 1);

    int anrows = (ach == 7) ? 21 : 25;
    int arow0 = bA * 196 + ach * 25;
    u16* Pg = gd.P + g * 262144;
    int ep = 0;

    for (int step = 0; step < T_; ++step) {
        // ================= stage A: hterm + attention MLP scores =================
        const u16* hsrcA = step ? (gd.hze + (size_t)(bA * T_ + step - 1) * 1280)
                                : (gd.h0b + bA * 512);
        {
            float2 hp = bfp(ldc32(hsrcA + 2 * t));
            su.hs[2 * t] = hp.x;
            su.hs[2 * t + 1] = hp.y;
        }
        __syncthreads();
        float htv;
        {
            float ha[8] = {0.f, 0.f, 0.f, 0.f, 0.f, 0.f, 0.f, 0.f};
            const u16* wp = gd.w1hT + (size_t)t * 512;
#pragma unroll 4
            for (int k = 0; k < 512; k += 8) {
                uint4 wv = *(const uint4*)(wp + k);
                float4 hA = *(const float4*)&su.hs[k];
                float4 hB = *(const float4*)&su.hs[k + 4];
                float2 w01 = bfp(wv.x), w23 = bfp(wv.y), w45 = bfp(wv.z), w67 = bfp(wv.w);
                ha[0] += hA.x * w01.x; ha[1] += hA.y * w01.y;
                ha[2] += hA.z * w23.x; ha[3] += hA.w * w23.y;
                ha[4] += hB.x * w45.x; ha[5] += hB.y * w45.y;
                ha[6] += hB.z * w67.x; ha[7] += hB.w * w67.y;
            }
            htv = ((ha[0] + ha[1]) + (ha[2] + ha[3])) + ((ha[4] + ha[5]) + (ha[6] + ha[7]));
        }
        __syncthreads();  // hs dead; reuse as x1s
        for (int rr = 0; rr < 28; ++rr) {
            float v = 0.f;
            if (rr < anrows) v = tanh_fast(bf2f(gd.pre1[(size_t)(arow0 + rr) * 256 + t]) + htv);
            su.a.x1s[rr][t] = v;
        }
        __syncthreads();
        if (t < 224) {
            int r0 = (t >> 5) * 4, c0v = (t & 31) * 4;
            float acc[4][4];
#pragma unroll
            for (int i = 0; i < 4; ++i)
#pragma unroll
                for (int j = 0; j < 4; ++j) acc[i][j] = 0.f;
            for (int k8 = 0; k8 < 256; k8 += 8) {
                uint4 wv[4];
#pragma unroll
                for (int j = 0; j < 4; ++j)
                    wv[j] = *(const uint4*)(gd.w2T + (size_t)(c0v + j) * 256 + k8);
                float4 xa[4], xb[4];
#pragma unroll
                for (int i = 0; i < 4; ++i) {
                    xa[i] = *(const float4*)&su.a.x1s[r0 + i][k8];
                    xb[i] = *(const float4*)&su.a.x1s[r0 + i][k8 + 4];
                }
#pragma unroll
                for (int j = 0; j < 4; ++j) {
                    float2 w0 = bfp(wv[j].x), w1 = bfp(wv[j].y);
                    float2 w2 = bfp(wv[j].z), w3 = bfp(wv[j].w);
#pragma unroll
                    for (int i = 0; i < 4; ++i)
                        acc[i][j] += xa[i].x * w0.x + xa[i].y * w0.y + xa[i].z * w1.x +
                                     xa[i].w * w1.y + xb[i].x * w2.x + xb[i].y * w2.y +
                                     xb[i].z * w3.x + xb[i].w * w3.y;
                }
            }
#pragma unroll
            for (int i = 0; i < 4; ++i) {
                float p = 0.f;
#pragma unroll
                for (int j = 0; j < 4; ++j)
                    p += tanh_fast(acc[i][j] + b2s[c0v + j]) * w3s[c0v + j];
                su.a.part[r0 + i][t & 31] = p;
            }
        }
        __syncthreads();
        if (t < anrows) {
            float s = 0.f;
#pragma unroll
            for (int cg = 0; cg < 32; ++cg) s += su.a.part[t][cg];
            stcf(&gd.s_buf[arow0 + t], s);  // att_b3 omitted: softmax-invariant
        }
        gbar(gd.bars, g, r, t, ++ep);
        // ================= stage B: softmax + context z =================
        {
            float v = (t < L_) ? ldcf(&gd.s_buf[bA * L_ + t]) : -1e30f;
            su.b.red[t] = v;
            __syncthreads();
            for (int off = 128; off > 0; off >>= 1) {
                if (t < off) su.b.red[t] = fmaxf(su.b.red[t], su.b.red[t + off]);
                __syncthreads();
            }
            float mx = su.b.red[0];
            __syncthreads();
            float e = (t < L_) ? __expf(v - mx) : 0.f;
            su.b.red[t] = e;
            __syncthreads();
            for (int off = 128; off > 0; off >>= 1) {
                if (t < off) su.b.red[t] += su.b.red[t + off];
                __syncthreads();
            }
            float inv = 1.f / su.b.red[0];
            __syncthreads();
            if (t < L_) su.b.alpha[t] = e * inv;
            __syncthreads();
            int dl = t >> 2, lq = t & 3;
            const u16* ap = gd.a + (size_t)bA * L_ * 512 + ach * 64 + dl;
            float zp = 0.f;
            int l0 = lq * 49;
            for (int l = l0; l < l0 + 49; ++l) zp += su.b.alpha[l] * bf2f(ap[(size_t)l * 512]);
            su.b.zred[dl][lq] = zp;
            __syncthreads();
            if (t < 32) {
                float z0 = su.b.zred[2 * t][0] + su.b.zred[2 * t][1] +
                           su.b.zred[2 * t][2] + su.b.zred[2 * t][3];
                float z1 = su.b.zred[2 * t + 1][0] + su.b.zred[2 * t + 1][1] +
                           su.b.zred[2 * t + 1][2] + su.b.zred[2 * t + 1][3];
                unsigned pk = (unsigned)f2bf(z0) | ((unsigned)f2bf(z1) << 16);
                stcu((unsigned*)(gd.hze + (size_t)(bA * T_ + step) * 1280 + 512 + ach * 64 + 2 * t),
                     pk);
            }
        }
        gbar(gd.bars, g, r, t, ++ep);
        // ========== gates: k-shard [40r,40r+40) x 2048 cols x 4 batches ==========
        if (t < 80) {  // stage x = [z|e|h] pairs into LDS
            int kk2 = t >> 2, b4 = t & 3;
            int k = kr0 + 2 * kk2;
            int b = g * 4 + b4;
            unsigned u;
            if (k < 512)
                u = ldc32(gd.hze + (size_t)(b * T_ + step) * 1280 + 512 + k);
            else if (k < 768)
                u = ldc32(gd.hze + (size_t)(b * T_ + step) * 1280 + 1024 + (k - 512));
            else
                u = step ? ldc32(gd.hze + (size_t)(b * T_ + step - 1) * 1280 + (k - 768))
                         : ldc32(gd.h0b + b * 512 + (k - 768));
            float2 x2 = bfp(u);
            xs[2 * kk2][b4] = x2.x;
            xs[2 * kk2 + 1][b4] = x2.y;
        }
        __syncthreads();
        {
            float acc[4][8];
#pragma unroll
            for (int b = 0; b < 4; ++b)
#pragma unroll
                for (int j = 0; j < 8; ++j) acc[b][j] = 0.f;
            const u16* wrow = gd.wS + (size_t)kr0 * 2048 + 8 * t;
#pragma unroll 2
            for (int kk = 0; kk < 40; ++kk) {
                uint4 wv = *(const uint4*)wrow;
                wrow += 2048;
                float2 w0 = bfp(wv.x), w1 = bfp(wv.y), w2 = bfp(wv.z), w3 = bfp(wv.w);
#pragma unroll
                for (int b = 0; b < 4; ++b) {
                    float x = xs[kk][b];
                    acc[b][0] += x * w0.x; acc[b][1] += x * w0.y;
                    acc[b][2] += x * w1.x; acc[b][3] += x * w1.y;
                    acc[b][4] += x * w2.x; acc[b][5] += x * w2.y;
                    acc[b][6] += x * w3.x; acc[b][7] += x * w3.y;
                }
            }
#pragma unroll
            for (int b = 0; b < 4; ++b) {  // coalesced bf16 partial write
                unsigned p01 = (unsigned)f2bf(acc[b][0]) | ((unsigned)f2bf(acc[b][1]) << 16);
                unsigned p23 = (unsigned)f2bf(acc[b][2]) | ((unsigned)f2bf(acc[b][3]) << 16);
                unsigned p45 = (unsigned)f2bf(acc[b][4]) | ((unsigned)f2bf(acc[b][5]) << 16);
                unsigned p67 = (unsigned)f2bf(acc[b][6]) | ((unsigned)f2bf(acc[b][7]) << 16);
                unsigned long long lo = (unsigned long long)p01 | ((unsigned long long)p23 << 32);
                unsigned long long hi = (unsigned long long)p45 | ((unsigned long long)p67 << 32);
                u16* pp = Pg + (size_t)(r * 4 + b) * 2048 + 8 * t;
                stcu64((unsigned long long*)pp, lo);
                stcu64((unsigned long long*)(pp + 4), hi);
            }
        }
        gbar(gd.bars, g, r, t, ++ep);
        // ========== sum partials + state update: h-dims [16r,16r+16) ==========
        if (t < 128) {
            int q = t >> 5, b4 = (t >> 3) & 3, i2 = t & 7;
            int col = q * 512 + 16 * r + 2 * i2;
            float s0 = 0.f, s1 = 0.f;
            for (int rr = 0; rr < 32; ++rr) {
                float2 p = bfp(ldc32(Pg + (size_t)(rr * 4 + b4) * 2048 + col));
                s0 += p.x;
                s1 += p.y;
            }
            gsum[q][b4][2 * i2] = s0;
            gsum[q][b4][2 * i2 + 1] = s1;
        }
        __syncthreads();
        if (t < 64) {
            int b4 = t >> 4, i = t & 15;
            int d = 16 * r + i, b = g * 4 + b4;
            float g0 = gsum[0][b4][i] + biasv[i];
            float g1 = gsum[1][b4][i] + biasv[16 + i];
            float g2 = gsum[2][b4][i] + biasv[32 + i];
            float g3 = gsum[3][b4][i] + biasv[48 + i];
            float gi = sigm(g0), gf = sigm(g1), gn = tanh_fast(g2), go = sigm(g3);
            float cn = gf * gd.c_buf[b * 512 + d] + gi * gn;
            gd.c_buf[b * 512 + d] = cn;  // block-private slice after init
            hsh2[b4][i] = go * tanh_fast(cn);
        }
        __syncthreads();
        if (t < 32) {
            int b4 = t >> 3, i2 = t & 7;
            int b = g * 4 + b4;
            unsigned pk = (unsigned)f2bf(hsh2[b4][2 * i2]) |
                          ((unsigned)f2bf(hsh2[b4][2 * i2 + 1]) << 16);
            stcu((unsigned*)(gd.hze + (size_t)(b * T_ + step) * 1280 + 16 * r + 2 * i2), pk);
        }
        gbar(gd.bars, g, r, t, ++ep);
    }
}

extern "C" void kernel_launch(void* const* d_in, const int* in_sizes, int n_in,
                              void* d_out, int out_size, void* d_ws, size_t ws_size,
                              hipStream_t stream) {
    (void)in_sizes; (void)n_in; (void)out_size; (void)ws_size;
    const int* y = (const int*)d_in[3];

    char* base = (char*)d_ws;
    size_t off = 0;
    auto alloc = [&](size_t bytes) {
        void* p = base + off;
        off = (off + bytes + 63) & ~(size_t)63;
        return p;
    };
    // Total ~33.6 MB — must stay <= 34.34 MB (round-2 proven bound).
    int* flg   = (int*)alloc(64);
    int* bars  = (int*)alloc(NBARS * 4);
    u16* conv  = (u16*)alloc((size_t)7067000 * 2);
    u16* pre1  = (u16*)alloc((size_t)6272 * 256 * 2);   // t2 aliases after decoder
    u16* hze   = (u16*)alloc((size_t)4096 * 1280 * 2);
    u16* wS    = (u16*)alloc((size_t)1280 * 2048 * 2);  // t1 aliases after decoder
    u16* w1hT  = (u16*)alloc((size_t)256 * 512 * 2);
    u16* w2T   = (u16*)alloc((size_t)128 * 256 * 2);
    u16* h0b   = (u16*)alloc((size_t)32 * 512 * 2);
    float* s_buf = (float*)alloc(32 * 196 * 4);
    float* c_buf = (float*)alloc(32 * 512 * 4);
    u16* t1 = wS;    // dead after decoder
    u16* t2 = pre1;  // dead after decoder

    u16* c_a     = conv + 0;
    u16* c_h0    = conv + 3211264;
    u16* c_c0    = conv + 3227648;
    u16* c_attw1 = conv + 3244032;
    u16* c_attb1 = conv + 3506176;
    u16* c_attw2 = conv + 3506432;
    u16* c_attb2 = conv + 3539200;
    u16* c_attw3 = conv + 3539328;
    u16* c_wih   = conv + 3539456;
    u16* c_whh   = conv + 5112320;
    u16* c_bih   = conv + 6160896;
    u16* c_bhh   = conv + 6162944;
    u16* c_emb   = conv + 6164992;
    u16* c_ow1   = conv + 6296064;
    u16* c_ob1   = conv + 6754304;
    u16* c_ow2   = conv + 6754664;
    u16* c_ob2   = conv + 6882832;
    u16* c_ow3   = conv + 6883192;
    u16* c_ob3   = conv + 7066488;
    // P (bf16 partials, 8 groups x 32 x 4 x 2048 = 2,097,152 elems) lives in the
    // dead c_wih/c_whh region (2,621,440 elems) — dead once prep builds wS.
    u16* P = c_wih;

    ConvPtrs cp;
    {
        const int idx[19] = {0, 1, 2, 4, 5, 6, 7, 8, 10, 11, 12, 13, 14, 15, 16, 17, 18, 19, 20};
        for (int i = 0; i < 19; ++i) cp.p[i] = d_in[idx[i]];
    }

    detect_kernel<<<1, 64, 0, stream>>>((const u16*)d_in[4], flg, bars);
    conv_kernel<<<6902, 256, 0, stream>>>(cp, flg, conv);
    prep_kernel<<<1664, 256, 0, stream>>>(c_wih, c_whh, c_attw1, c_attw2, wS, w1hT, w2T);
    embed_kernel<<<1024, 256, 0, stream>>>(y, c_emb, hze);
    gemm_kernel<false, 1><<<dim3(4, 49), 256, 0, stream>>>(
        c_a, 512, c_attw1, 256, c_attb1, pre1, 256, 6272, 256, 512, flg);

    DecArgs g;
    g.h0 = c_h0; g.c0 = c_c0; g.pre1 = pre1; g.w2T = w2T; g.att_b2 = c_attb2;
    g.att_w3 = c_attw3; g.w1hT = w1hT; g.wS = wS; g.bih = c_bih; g.bhh = c_bhh;
    g.a = c_a; g.hze = hze; g.h0b = h0b; g.P = P; g.s_buf = s_buf; g.c_buf = c_buf;
    g.bars = bars;
    decoder_kernel<<<GRID_, 256, 0, stream>>>(g);

    gemm_kernel<true, 1><<<dim3(6, 32), 256, 0, stream>>>(
        hze, 1280, c_ow1, 358, c_ob1, t1, 358, 4096, 358, 1280, flg);
    gemm_kernel<true, 1><<<dim3(6, 32), 256, 0, stream>>>(
        t1, 358, c_ow2, 358, c_ob2, t2, 358, 4096, 358, 358, flg);
    gemm_kernel<false, 2><<<dim3(8, 32), 256, 0, stream>>>(
        t2, 358, c_ow3, 512, c_ob3, d_out, 512, 4096, 512, 358, flg);
}